// Round 13
// baseline (341.377 us; speedup 1.0000x reference)
//
#include <hip/hip_runtime.h>

#define N_NODES 50000
#define C_FEAT  64
#define E_EDGES 800000
#define KEYS    400000          // dst*8 + t
#define NBLK1   391             // ceil(KEYS/1024)
#define DPB     16              // dsts per conv block -> 16 MFMA rows
#define PBLK_X  1563            // x->bf16 cvt blocks (8 elems/thread, last partial)
#define PBLK_W  128             // Wt transpose blocks
#define PBLK_A  64              // Wa1T/Wa2T transpose blocks (2 x 8192)
#define PBLK_H  3125            // hist blocks

typedef __attribute__((ext_vector_type(8))) short short8;
typedef __attribute__((ext_vector_type(4))) float f32x4;

__device__ __forceinline__ float bf2f(unsigned short u) {
    union { unsigned int i; float f; } v; v.i = ((unsigned int)u) << 16; return v.f;
}
__device__ __forceinline__ unsigned short f2bf(float f) {
    union { float f; unsigned int i; } v; v.f = f;
    unsigned int r = v.i + 0x7fff + ((v.i >> 16) & 1);   // RNE
    return (unsigned short)(r >> 16);
}

// -------- prep (x->bf16, Wt->WT bf16, Wa->WaT bf16) + hist, block-range fused --------
__global__ __launch_bounds__(256) void prep_hist(const float* __restrict__ x,
                                                 const float* __restrict__ W1,
                                                 const float* __restrict__ W2,
                                                 const float* __restrict__ Wa1,
                                                 const float* __restrict__ Wa2,
                                                 const int* __restrict__ dst,
                                                 const int* __restrict__ tix,
                                                 unsigned short* __restrict__ xb,
                                                 unsigned short* __restrict__ WT1,
                                                 unsigned short* __restrict__ WT2,
                                                 unsigned short* __restrict__ Wa1T,
                                                 unsigned short* __restrict__ Wa2T,
                                                 int* __restrict__ cnt) {
    const int b = blockIdx.x;
    if (b < PBLK_X) {
        int base = (b * 256 + threadIdx.x) * 8;
        if (base < N_NODES * 64) {                     // guard last partial block
            float4 a = *(const float4*)(x + base);
            float4 c = *(const float4*)(x + base + 4);
            short8 o;
            o[0] = (short)f2bf(a.x); o[1] = (short)f2bf(a.y);
            o[2] = (short)f2bf(a.z); o[3] = (short)f2bf(a.w);
            o[4] = (short)f2bf(c.x); o[5] = (short)f2bf(c.y);
            o[6] = (short)f2bf(c.z); o[7] = (short)f2bf(c.w);
            *(short8*)(xb + base) = o;
        }
    } else if (b < PBLK_X + PBLK_W) {
        int i = (b - PBLK_X) * 256 + threadIdx.x;      // 32768
        int n = i >> 9, k = i & 511;
        WT1[i] = f2bf(W1[k * 64 + n]);
        WT2[i] = f2bf(W2[k * 64 + n]);
    } else if (b < PBLK_X + PBLK_W + PBLK_A) {
        int i = (b - PBLK_X - PBLK_W) * 256 + threadIdx.x;   // 0..16383
        if (i < 8192) {                                // Wa1T[128][64] <- Wa1[64][128]
            int n = i >> 6, k = i & 63;
            Wa1T[i] = f2bf(Wa1[k * 128 + n]);
        } else {                                       // Wa2T[64][128] <- Wa2[128][64]
            int ii = i - 8192;
            int n = ii >> 7, k = ii & 127;
            Wa2T[ii] = f2bf(Wa2[k * 64 + n]);
        }
    } else {
        int e = (b - PBLK_X - PBLK_W - PBLK_A) * 256 + threadIdx.x;
        if (e < E_EDGES) atomicAdd(&cnt[dst[e] * 8 + tix[e]], 1);
    }
}

// -------- scan_all: per-chunk local scan; LAST block scans chunk totals --------
__global__ __launch_bounds__(256) void scan_all(int* __restrict__ cnt,
                                                int* __restrict__ bsum,
                                                int* __restrict__ chunkoff,
                                                int* __restrict__ done) {
    __shared__ int wsum[4];
    __shared__ int ticket;
    const int tid = threadIdx.x;
    const int lane = tid & 63;
    const int wave = tid >> 6;
    const int i4 = blockIdx.x * 256 + tid;
    int4 v = make_int4(0, 0, 0, 0);
    const bool ok = (i4 * 4 < KEYS);
    if (ok) v = ((const int4*)cnt)[i4];
    int s = v.x + v.y + v.z + v.w;
    int sc = s;
    #pragma unroll
    for (int d = 1; d < 64; d <<= 1) {
        int o = __shfl_up(sc, d, 64);
        if (lane >= d) sc += o;
    }
    if (lane == 63) wsum[wave] = sc;
    __syncthreads();
    int wbase = 0;
    #pragma unroll
    for (int w = 0; w < 4; ++w) wbase += (w < wave) ? wsum[w] : 0;
    int base = wbase + sc - s;
    int4 o;
    o.x = base;
    o.y = base + v.x;
    o.z = o.y + v.y;
    o.w = o.z + v.z;
    if (ok) ((int4*)cnt)[i4] = o;
    if (tid == 255) {
        bsum[blockIdx.x] = wbase + sc;
        __threadfence();
        ticket = atomicAdd(done, 1);
    }
    __syncthreads();
    if (ticket == NBLK1 - 1 && wave == 0) {
        int carry = 0;
        #pragma unroll
        for (int g = 0; g < (NBLK1 + 63) / 64; ++g) {
            int j = g * 64 + lane;
            int val = (j < NBLK1) ? atomicAdd(&bsum[j], 0) : 0;
            int scn = val;
            #pragma unroll
            for (int d = 1; d < 64; d <<= 1) {
                int oo = __shfl_up(scn, d, 64);
                if (lane >= d) scn += oo;
            }
            if (j < NBLK1) chunkoff[j] = carry + scn - val;
            carry += __shfl(scn, 63, 64);
        }
    }
}

// cursor advance on LOCAL offsets; global pos = chunkoff[chunk] + local.
__global__ __launch_bounds__(256) void scatter_edges(const int* __restrict__ src,
                                                     const int* __restrict__ dst,
                                                     const int* __restrict__ tix,
                                                     int* __restrict__ cursor,
                                                     const int* __restrict__ chunkoff,
                                                     int* __restrict__ elist) {
    int e = blockIdx.x * 256 + threadIdx.x;
    if (e >= E_EDGES) return;
    int t = tix[e];
    int key = dst[e] * 8 + t;
    int pos = chunkoff[key >> 10] + atomicAdd(&cursor[key], 1);
    __builtin_nontemporal_store(src[e] | (t << 16), &elist[pos]);  // no-allocate: cut line-fill amp
}

// -------- fused conv: 512 threads, 8 waves x 2 dsts, unroll-16 gather, MFMA --------
#define FLUSH(T, V)                                                                   \
    { int _t = (T);                                                                   \
      if (_t != cur) { scat[dl][cur * 64 + c] = f2bf(acc); acc = 0.f; cur = _t; }     \
      acc += (V); }

#define EDGE(K)                                                                       \
    int p##K = __builtin_amdgcn_readlane(pv, e + K);                                  \
    float v##K = bf2f(Xb[(size_t)(p##K & 0xffff) * 64 + c]);

__global__ __launch_bounds__(512, 4) void fused_conv(const unsigned short* __restrict__ Xb,
                                                     const unsigned short* __restrict__ WT,
                                                     const float* __restrict__ bias,
                                                     const int* __restrict__ segend,   // local ends
                                                     const int* __restrict__ chunkoff,
                                                     const int* __restrict__ elist,
                                                     unsigned short* __restrict__ Hb) {
    __shared__ unsigned short scat[DPB][520];
    const int lane = threadIdx.x & 63;
    const int wave = threadIdx.x >> 6;               // 0..7
    const int dbase = blockIdx.x * DPB;
    const int c = lane;

    {   // zero own 2 rows
        short8 z = {};
        *(short8*)&scat[wave * 2 + 0][lane * 8] = z;
        *(short8*)&scat[wave * 2 + 1][lane * 8] = z;
    }

    int sbeg[2], send_[2], pvw[2];
    #pragma unroll
    for (int q = 0; q < 2; ++q) {
        const int d = dbase + wave * 2 + q;
        const int k0 = d * 8;
        sbeg[q]  = (d == 0) ? 0 : chunkoff[(k0 - 1) >> 10] + segend[k0 - 1];
        send_[q] = chunkoff[(k0 + 7) >> 10] + segend[k0 + 7];
    }
    #pragma unroll
    for (int q = 0; q < 2; ++q)
        pvw[q] = (lane < send_[q] - sbeg[q]) ? elist[sbeg[q] + lane] : 0;

    #pragma unroll
    for (int q = 0; q < 2; ++q) {
        const int dl = wave * 2 + q;
        int i = sbeg[q];
        const int end = send_[q];
        int pv = pvw[q];
        int cur = 0;
        float acc = 0.f;
        while (i < end) {
            int cnt = end - i; cnt = (cnt > 64) ? 64 : cnt;
            int e = 0;
            for (; e + 15 < cnt; e += 16) {          // 16 gathers in flight
                EDGE(0) EDGE(1) EDGE(2) EDGE(3) EDGE(4) EDGE(5) EDGE(6) EDGE(7)
                EDGE(8) EDGE(9) EDGE(10) EDGE(11) EDGE(12) EDGE(13) EDGE(14) EDGE(15)
                FLUSH(p0 >> 16, v0)   FLUSH(p1 >> 16, v1)
                FLUSH(p2 >> 16, v2)   FLUSH(p3 >> 16, v3)
                FLUSH(p4 >> 16, v4)   FLUSH(p5 >> 16, v5)
                FLUSH(p6 >> 16, v6)   FLUSH(p7 >> 16, v7)
                FLUSH(p8 >> 16, v8)   FLUSH(p9 >> 16, v9)
                FLUSH(p10 >> 16, v10) FLUSH(p11 >> 16, v11)
                FLUSH(p12 >> 16, v12) FLUSH(p13 >> 16, v13)
                FLUSH(p14 >> 16, v14) FLUSH(p15 >> 16, v15)
            }
            for (; e < cnt; ++e) {
                EDGE(0)
                FLUSH(p0 >> 16, v0)
            }
            i += 64;
            if (i < end) pv = (lane < end - i) ? elist[i + lane] : 0;
        }
        scat[dl][cur * 64 + c] = f2bf(acc);
    }
    __syncthreads();

    // MFMA [16,512]@[512,64] on waves 0..3; C/D col=lane&15, row=quad*4+r (m89/m91)
    if (wave < 4) {
        const int m = lane & 15;
        const int quad = lane >> 4;
        const int n0 = wave * 16;
        f32x4 acc4 = {0.f, 0.f, 0.f, 0.f};
        const unsigned short* wrow = WT + (size_t)(n0 + m) * 512;
        #pragma unroll
        for (int kc = 0; kc < 16; ++kc) {
            short8 af = *(const short8*)&scat[m][kc * 32 + quad * 8];
            short8 bf = *(const short8*)(wrow + kc * 32 + quad * 8);
            acc4 = __builtin_amdgcn_mfma_f32_16x16x32_bf16(af, bf, acc4, 0, 0, 0);
        }
        const int col = n0 + m;
        const float bcol = bias[col];
        #pragma unroll
        for (int r = 0; r < 4; ++r) {
            int node = dbase + quad * 4 + r;
            Hb[(size_t)node * 64 + col] = f2bf(fmaxf(acc4[r] + bcol, 0.f));
        }
    }
}

// -------- adversary MLP via MFMA + h1 residual: out = relu(h2@Wa1+ba1)@Wa2+ba2+h1 --------
// 64 nodes/block, 4 waves; wave w owns rows w*16..w*16+15.
__global__ __launch_bounds__(256) void adv_mfma(const unsigned short* __restrict__ h2b,
                                                const unsigned short* __restrict__ Wa1T, // [128][64] bf16
                                                const float* __restrict__ ba1,           // [128]
                                                const unsigned short* __restrict__ Wa2T, // [64][128] bf16
                                                const float* __restrict__ ba2,           // [64]
                                                const unsigned short* __restrict__ h1b,
                                                float* __restrict__ out) {
    __shared__ unsigned short sH[64][72];    // h2 tile bf16
    __shared__ unsigned short sT[64][136];   // relu(h2@Wa1+ba1) bf16
    const int nbase = blockIdx.x * 64;
    const int tid = threadIdx.x;
    const int lane = tid & 63;
    const int wave = tid >> 6;
    const int m = lane & 15;
    const int quad = lane >> 4;
    const int r0 = wave * 16;

    // stage h2 tile (bf16 passthrough)
    #pragma unroll
    for (int i = 0; i < 2; ++i) {
        int idx = tid * 2 + i;               // 512 short8 loads
        int row = idx >> 3;
        int c8  = (idx & 7) * 8;
        int node = nbase + row;
        short8 u = {};
        if (node < N_NODES)
            u = *(const short8*)(h2b + (size_t)node * C_FEAT + c8);
        *(short8*)&sH[row][c8] = u;
    }
    __syncthreads();

    // GEMM1: [16,64] @ [64,128] per wave -> sT rows r0..r0+15
    {
        f32x4 acc1[8];
        #pragma unroll
        for (int ct = 0; ct < 8; ++ct) acc1[ct] = (f32x4){0.f, 0.f, 0.f, 0.f};
        #pragma unroll
        for (int kc = 0; kc < 2; ++kc) {
            short8 af = *(const short8*)&sH[r0 + m][kc * 32 + quad * 8];
            #pragma unroll
            for (int ct = 0; ct < 8; ++ct) {
                short8 bf = *(const short8*)(Wa1T + (size_t)(ct * 16 + m) * 64 + kc * 32 + quad * 8);
                acc1[ct] = __builtin_amdgcn_mfma_f32_16x16x32_bf16(af, bf, acc1[ct], 0, 0, 0);
            }
        }
        #pragma unroll
        for (int ct = 0; ct < 8; ++ct) {
            const int col = ct * 16 + m;
            const float b1 = ba1[col];
            #pragma unroll
            for (int r = 0; r < 4; ++r)
                sT[r0 + quad * 4 + r][col] = f2bf(fmaxf(acc1[ct][r] + b1, 0.f));
        }
    }
    __syncthreads();

    // GEMM2: [16,128] @ [128,64] per wave -> out rows r0..r0+15 (+ba2 +h1)
    {
        f32x4 acc2[4];
        #pragma unroll
        for (int ct = 0; ct < 4; ++ct) acc2[ct] = (f32x4){0.f, 0.f, 0.f, 0.f};
        #pragma unroll
        for (int kc = 0; kc < 4; ++kc) {
            short8 af = *(const short8*)&sT[r0 + m][kc * 32 + quad * 8];
            #pragma unroll
            for (int ct = 0; ct < 4; ++ct) {
                short8 bf = *(const short8*)(Wa2T + (size_t)(ct * 16 + m) * 128 + kc * 32 + quad * 8);
                acc2[ct] = __builtin_amdgcn_mfma_f32_16x16x32_bf16(af, bf, acc2[ct], 0, 0, 0);
            }
        }
        #pragma unroll
        for (int ct = 0; ct < 4; ++ct) {
            const int col = ct * 16 + m;
            const float b2 = ba2[col];
            #pragma unroll
            for (int r = 0; r < 4; ++r) {
                int node = nbase + r0 + quad * 4 + r;
                if (node < N_NODES) {
                    float val = acc2[ct][r] + b2 + bf2f(h1b[(size_t)node * 64 + col]);
                    out[(size_t)node * 64 + col] = val;
                }
            }
        }
    }
}

extern "C" void kernel_launch(void* const* d_in, const int* in_sizes, int n_in,
                              void* d_out, int out_size, void* d_ws, size_t ws_size,
                              hipStream_t stream) {
    const float* x   = (const float*)d_in[0];
    const int*   ei  = (const int*)d_in[1];
    const int*   tix = (const int*)d_in[2];
    const float* Wt1 = (const float*)d_in[3];
    const float* bt1 = (const float*)d_in[4];
    const float* Wt2 = (const float*)d_in[5];
    const float* bt2 = (const float*)d_in[6];
    const float* Wa1 = (const float*)d_in[7];
    const float* ba1 = (const float*)d_in[8];
    const float* Wa2 = (const float*)d_in[9];
    const float* ba2 = (const float*)d_in[10];
    float* out = (float*)d_out;

    const int* src = ei;
    const int* dst = ei + E_EDGES;

    // workspace (~25 MB)
    unsigned short* xb   = (unsigned short*)d_ws;          // [N,64] bf16
    unsigned short* h1b  = xb + (size_t)N_NODES * 64;      // [N,64] bf16
    unsigned short* h2b  = h1b + (size_t)N_NODES * 64;     // [N,64] bf16
    unsigned short* WT1  = h2b + (size_t)N_NODES * 64;     // [64,512] bf16
    unsigned short* WT2  = WT1 + 64 * 512;
    unsigned short* Wa1T = WT2 + 64 * 512;                 // [128,64] bf16
    unsigned short* Wa2T = Wa1T + 8192;                    // [64,128] bf16
    int* cnt      = (int*)(Wa2T + 8192);                   // KEYS
    int* bsum     = cnt + KEYS;                            // 512
    int* chunkoff = bsum + 512;                            // 512
    int* done     = chunkoff + 512;                        // 64 (1 used)
    int* elist    = done + 64;                             // E packed (src | t<<16)

    const int eBlk = (E_EDGES + 255) / 256;               // 3125
    const int cBlk = N_NODES / DPB;                       // 3125 (exact)
    const int aBlk = (N_NODES + 63) / 64;                 // 782

    hipMemsetAsync(cnt, 0, (KEYS + 512 + 512 + 64) * sizeof(int), stream);
    prep_hist<<<PBLK_X + PBLK_W + PBLK_A + PBLK_H, 256, 0, stream>>>(
        x, Wt1, Wt2, Wa1, Wa2, dst, tix, xb, WT1, WT2, Wa1T, Wa2T, cnt);
    scan_all<<<NBLK1, 256, 0, stream>>>(cnt, bsum, chunkoff, done);
    scatter_edges<<<eBlk, 256, 0, stream>>>(src, dst, tix, cnt, chunkoff, elist);

    fused_conv<<<cBlk, 512, 0, stream>>>(xb,  WT1, bt1, cnt, chunkoff, elist, h1b);
    fused_conv<<<cBlk, 512, 0, stream>>>(h1b, WT2, bt2, cnt, chunkoff, elist, h2b);

    adv_mfma<<<aBlk, 256, 0, stream>>>(h2b, Wa1T, ba1, Wa2T, ba2, h1b, out);
}

// Round 14
// 313.666 us; speedup vs baseline: 1.0883x; 1.0883x over previous
//
#include <hip/hip_runtime.h>

#define N_NODES 50000
#define C_FEAT  64
#define E_EDGES 800000
#define KEYS    400000          // dst*8 + t
#define NBLK1   391             // ceil(KEYS/1024)
#define DPB     16              // dsts per conv block -> 16 MFMA rows
#define PBLK_X  1563            // x->bf16 cvt blocks (8 elems/thread, last partial)
#define PBLK_W  128             // Wt transpose blocks
#define PBLK_A  64              // Wa1T/Wa2T transpose blocks (2 x 8192)
#define PBLK_H  3125            // hist blocks

typedef __attribute__((ext_vector_type(8))) short short8;
typedef __attribute__((ext_vector_type(4))) float f32x4;

__device__ __forceinline__ float bf2f(unsigned short u) {
    union { unsigned int i; float f; } v; v.i = ((unsigned int)u) << 16; return v.f;
}
__device__ __forceinline__ unsigned short f2bf(float f) {
    union { float f; unsigned int i; } v; v.f = f;
    unsigned int r = v.i + 0x7fff + ((v.i >> 16) & 1);   // RNE
    return (unsigned short)(r >> 16);
}

// -------- prep (x->bf16, Wt->WT bf16, Wa->WaT bf16) + hist, block-range fused --------
__global__ __launch_bounds__(256) void prep_hist(const float* __restrict__ x,
                                                 const float* __restrict__ W1,
                                                 const float* __restrict__ W2,
                                                 const float* __restrict__ Wa1,
                                                 const float* __restrict__ Wa2,
                                                 const int* __restrict__ dst,
                                                 const int* __restrict__ tix,
                                                 unsigned short* __restrict__ xb,
                                                 unsigned short* __restrict__ WT1,
                                                 unsigned short* __restrict__ WT2,
                                                 unsigned short* __restrict__ Wa1T,
                                                 unsigned short* __restrict__ Wa2T,
                                                 int* __restrict__ cnt) {
    const int b = blockIdx.x;
    if (b < PBLK_X) {
        int base = (b * 256 + threadIdx.x) * 8;
        if (base < N_NODES * 64) {
            float4 a = *(const float4*)(x + base);
            float4 c = *(const float4*)(x + base + 4);
            short8 o;
            o[0] = (short)f2bf(a.x); o[1] = (short)f2bf(a.y);
            o[2] = (short)f2bf(a.z); o[3] = (short)f2bf(a.w);
            o[4] = (short)f2bf(c.x); o[5] = (short)f2bf(c.y);
            o[6] = (short)f2bf(c.z); o[7] = (short)f2bf(c.w);
            *(short8*)(xb + base) = o;
        }
    } else if (b < PBLK_X + PBLK_W) {
        int i = (b - PBLK_X) * 256 + threadIdx.x;      // 32768
        int n = i >> 9, k = i & 511;
        WT1[i] = f2bf(W1[k * 64 + n]);
        WT2[i] = f2bf(W2[k * 64 + n]);
    } else if (b < PBLK_X + PBLK_W + PBLK_A) {
        int i = (b - PBLK_X - PBLK_W) * 256 + threadIdx.x;   // 0..16383
        if (i < 8192) {                                // Wa1T[128][64] <- Wa1[64][128]
            int n = i >> 6, k = i & 63;
            Wa1T[i] = f2bf(Wa1[k * 128 + n]);
        } else {                                       // Wa2T[64][128] <- Wa2[128][64]
            int ii = i - 8192;
            int n = ii >> 7, k = ii & 127;
            Wa2T[ii] = f2bf(Wa2[k * 64 + n]);
        }
    } else {
        int e = (b - PBLK_X - PBLK_W - PBLK_A) * 256 + threadIdx.x;
        if (e < E_EDGES) atomicAdd(&cnt[dst[e] * 8 + tix[e]], 1);
    }
}

// -------- scan_all: per-chunk local scan; LAST block scans chunk totals --------
__global__ __launch_bounds__(256) void scan_all(int* __restrict__ cnt,
                                                int* __restrict__ bsum,
                                                int* __restrict__ chunkoff,
                                                int* __restrict__ done) {
    __shared__ int wsum[4];
    __shared__ int ticket;
    const int tid = threadIdx.x;
    const int lane = tid & 63;
    const int wave = tid >> 6;
    const int i4 = blockIdx.x * 256 + tid;
    int4 v = make_int4(0, 0, 0, 0);
    const bool ok = (i4 * 4 < KEYS);
    if (ok) v = ((const int4*)cnt)[i4];
    int s = v.x + v.y + v.z + v.w;
    int sc = s;
    #pragma unroll
    for (int d = 1; d < 64; d <<= 1) {
        int o = __shfl_up(sc, d, 64);
        if (lane >= d) sc += o;
    }
    if (lane == 63) wsum[wave] = sc;
    __syncthreads();
    int wbase = 0;
    #pragma unroll
    for (int w = 0; w < 4; ++w) wbase += (w < wave) ? wsum[w] : 0;
    int base = wbase + sc - s;
    int4 o;
    o.x = base;
    o.y = base + v.x;
    o.z = o.y + v.y;
    o.w = o.z + v.z;
    if (ok) ((int4*)cnt)[i4] = o;
    if (tid == 255) {
        bsum[blockIdx.x] = wbase + sc;
        __threadfence();
        ticket = atomicAdd(done, 1);
    }
    __syncthreads();
    if (ticket == NBLK1 - 1 && wave == 0) {
        int carry = 0;
        #pragma unroll
        for (int g = 0; g < (NBLK1 + 63) / 64; ++g) {
            int j = g * 64 + lane;
            int val = (j < NBLK1) ? atomicAdd(&bsum[j], 0) : 0;
            int scn = val;
            #pragma unroll
            for (int d = 1; d < 64; d <<= 1) {
                int oo = __shfl_up(scn, d, 64);
                if (lane >= d) scn += oo;
            }
            if (j < NBLK1) chunkoff[j] = carry + scn - val;
            carry += __shfl(scn, 63, 64);
        }
    }
}

// cursor advance on LOCAL offsets; global pos = chunkoff[chunk] + local.
__global__ __launch_bounds__(256) void scatter_edges(const int* __restrict__ src,
                                                     const int* __restrict__ dst,
                                                     const int* __restrict__ tix,
                                                     int* __restrict__ cursor,
                                                     const int* __restrict__ chunkoff,
                                                     int* __restrict__ elist) {
    int e = blockIdx.x * 256 + threadIdx.x;
    if (e >= E_EDGES) return;
    int t = tix[e];
    int key = dst[e] * 8 + t;
    int pos = chunkoff[key >> 10] + atomicAdd(&cursor[key], 1);
    __builtin_nontemporal_store(src[e] | (t << 16), &elist[pos]);
}

// -------- fused conv: 512 threads, 8 waves x 2 dsts, unroll 8/4/2/1, MFMA --------
#define FLUSH(T, V)                                                                   \
    { int _t = (T);                                                                   \
      if (_t != cur) { scat[dl][cur * 64 + c] = f2bf(acc); acc = 0.f; cur = _t; }     \
      acc += (V); }

#define EDGE(K)                                                                       \
    int p##K = __builtin_amdgcn_readlane(pv, e + K);                                  \
    float v##K = bf2f(Xb[(size_t)(p##K & 0xffff) * 64 + c]);

__global__ __launch_bounds__(512, 8) void fused_conv(const unsigned short* __restrict__ Xb,
                                                     const unsigned short* __restrict__ WT,
                                                     const float* __restrict__ bias,
                                                     const int* __restrict__ segend,   // local ends
                                                     const int* __restrict__ chunkoff,
                                                     const int* __restrict__ elist,
                                                     unsigned short* __restrict__ Hb) {
    __shared__ unsigned short scat[DPB][520];
    const int lane = threadIdx.x & 63;
    const int wave = threadIdx.x >> 6;               // 0..7
    const int dbase = blockIdx.x * DPB;
    const int c = lane;

    {   // zero own 2 rows
        short8 z = {};
        *(short8*)&scat[wave * 2 + 0][lane * 8] = z;
        *(short8*)&scat[wave * 2 + 1][lane * 8] = z;
    }

    int sbeg[2], send_[2], pvw[2];
    #pragma unroll
    for (int q = 0; q < 2; ++q) {
        const int d = dbase + wave * 2 + q;
        const int k0 = d * 8;
        sbeg[q]  = (d == 0) ? 0 : chunkoff[(k0 - 1) >> 10] + segend[k0 - 1];
        send_[q] = chunkoff[(k0 + 7) >> 10] + segend[k0 + 7];
    }
    #pragma unroll
    for (int q = 0; q < 2; ++q)
        pvw[q] = (lane < send_[q] - sbeg[q]) ? elist[sbeg[q] + lane] : 0;

    #pragma unroll
    for (int q = 0; q < 2; ++q) {
        const int dl = wave * 2 + q;
        int i = sbeg[q];
        const int end = send_[q];
        int pv = pvw[q];
        int cur = 0;
        float acc = 0.f;
        while (i < end) {
            int cnt = end - i; cnt = (cnt > 64) ? 64 : cnt;
            int e = 0;
            for (; e + 7 < cnt; e += 8) {
                EDGE(0) EDGE(1) EDGE(2) EDGE(3) EDGE(4) EDGE(5) EDGE(6) EDGE(7)
                FLUSH(p0 >> 16, v0) FLUSH(p1 >> 16, v1)
                FLUSH(p2 >> 16, v2) FLUSH(p3 >> 16, v3)
                FLUSH(p4 >> 16, v4) FLUSH(p5 >> 16, v5)
                FLUSH(p6 >> 16, v6) FLUSH(p7 >> 16, v7)
            }
            if (e + 3 < cnt) {                        // tail tier 4
                EDGE(0) EDGE(1) EDGE(2) EDGE(3)
                FLUSH(p0 >> 16, v0) FLUSH(p1 >> 16, v1)
                FLUSH(p2 >> 16, v2) FLUSH(p3 >> 16, v3)
                e += 4;
            }
            if (e + 1 < cnt) {                        // tail tier 2
                EDGE(0) EDGE(1)
                FLUSH(p0 >> 16, v0) FLUSH(p1 >> 16, v1)
                e += 2;
            }
            if (e < cnt) {                            // tail tier 1
                EDGE(0)
                FLUSH(p0 >> 16, v0)
            }
            i += 64;
            if (i < end) pv = (lane < end - i) ? elist[i + lane] : 0;
        }
        scat[dl][cur * 64 + c] = f2bf(acc);
    }
    __syncthreads();

    // MFMA [16,512]@[512,64] on waves 0..3; C/D col=lane&15, row=quad*4+r (m89/m91)
    if (wave < 4) {
        const int m = lane & 15;
        const int quad = lane >> 4;
        const int n0 = wave * 16;
        f32x4 acc4 = {0.f, 0.f, 0.f, 0.f};
        const unsigned short* wrow = WT + (size_t)(n0 + m) * 512;
        #pragma unroll
        for (int kc = 0; kc < 16; ++kc) {
            short8 af = *(const short8*)&scat[m][kc * 32 + quad * 8];
            short8 bf = *(const short8*)(wrow + kc * 32 + quad * 8);
            acc4 = __builtin_amdgcn_mfma_f32_16x16x32_bf16(af, bf, acc4, 0, 0, 0);
        }
        const int col = n0 + m;
        const float bcol = bias[col];
        #pragma unroll
        for (int r = 0; r < 4; ++r) {
            int node = dbase + quad * 4 + r;
            Hb[(size_t)node * 64 + col] = f2bf(fmaxf(acc4[r] + bcol, 0.f));
        }
    }
}

// -------- adversary MLP via MFMA + h1 residual (R13-proven) --------
__global__ __launch_bounds__(256) void adv_mfma(const unsigned short* __restrict__ h2b,
                                                const unsigned short* __restrict__ Wa1T, // [128][64] bf16
                                                const float* __restrict__ ba1,           // [128]
                                                const unsigned short* __restrict__ Wa2T, // [64][128] bf16
                                                const float* __restrict__ ba2,           // [64]
                                                const unsigned short* __restrict__ h1b,
                                                float* __restrict__ out) {
    __shared__ unsigned short sH[64][72];
    __shared__ unsigned short sT[64][136];
    const int nbase = blockIdx.x * 64;
    const int tid = threadIdx.x;
    const int lane = tid & 63;
    const int wave = tid >> 6;
    const int m = lane & 15;
    const int quad = lane >> 4;
    const int r0 = wave * 16;

    #pragma unroll
    for (int i = 0; i < 2; ++i) {
        int idx = tid * 2 + i;
        int row = idx >> 3;
        int c8  = (idx & 7) * 8;
        int node = nbase + row;
        short8 u = {};
        if (node < N_NODES)
            u = *(const short8*)(h2b + (size_t)node * C_FEAT + c8);
        *(short8*)&sH[row][c8] = u;
    }
    __syncthreads();

    {   // GEMM1: [16,64] @ [64,128] per wave -> sT rows r0..r0+15
        f32x4 acc1[8];
        #pragma unroll
        for (int ct = 0; ct < 8; ++ct) acc1[ct] = (f32x4){0.f, 0.f, 0.f, 0.f};
        #pragma unroll
        for (int kc = 0; kc < 2; ++kc) {
            short8 af = *(const short8*)&sH[r0 + m][kc * 32 + quad * 8];
            #pragma unroll
            for (int ct = 0; ct < 8; ++ct) {
                short8 bf = *(const short8*)(Wa1T + (size_t)(ct * 16 + m) * 64 + kc * 32 + quad * 8);
                acc1[ct] = __builtin_amdgcn_mfma_f32_16x16x32_bf16(af, bf, acc1[ct], 0, 0, 0);
            }
        }
        #pragma unroll
        for (int ct = 0; ct < 8; ++ct) {
            const int col = ct * 16 + m;
            const float b1 = ba1[col];
            #pragma unroll
            for (int r = 0; r < 4; ++r)
                sT[r0 + quad * 4 + r][col] = f2bf(fmaxf(acc1[ct][r] + b1, 0.f));
        }
    }
    __syncthreads();

    {   // GEMM2: [16,128] @ [128,64] per wave -> out rows r0..r0+15 (+ba2 +h1)
        f32x4 acc2[4];
        #pragma unroll
        for (int ct = 0; ct < 4; ++ct) acc2[ct] = (f32x4){0.f, 0.f, 0.f, 0.f};
        #pragma unroll
        for (int kc = 0; kc < 4; ++kc) {
            short8 af = *(const short8*)&sT[r0 + m][kc * 32 + quad * 8];
            #pragma unroll
            for (int ct = 0; ct < 4; ++ct) {
                short8 bf = *(const short8*)(Wa2T + (size_t)(ct * 16 + m) * 128 + kc * 32 + quad * 8);
                acc2[ct] = __builtin_amdgcn_mfma_f32_16x16x32_bf16(af, bf, acc2[ct], 0, 0, 0);
            }
        }
        #pragma unroll
        for (int ct = 0; ct < 4; ++ct) {
            const int col = ct * 16 + m;
            const float b2 = ba2[col];
            #pragma unroll
            for (int r = 0; r < 4; ++r) {
                int node = nbase + r0 + quad * 4 + r;
                if (node < N_NODES) {
                    float val = acc2[ct][r] + b2 + bf2f(h1b[(size_t)node * 64 + col]);
                    out[(size_t)node * 64 + col] = val;
                }
            }
        }
    }
}

extern "C" void kernel_launch(void* const* d_in, const int* in_sizes, int n_in,
                              void* d_out, int out_size, void* d_ws, size_t ws_size,
                              hipStream_t stream) {
    const float* x   = (const float*)d_in[0];
    const int*   ei  = (const int*)d_in[1];
    const int*   tix = (const int*)d_in[2];
    const float* Wt1 = (const float*)d_in[3];
    const float* bt1 = (const float*)d_in[4];
    const float* Wt2 = (const float*)d_in[5];
    const float* bt2 = (const float*)d_in[6];
    const float* Wa1 = (const float*)d_in[7];
    const float* ba1 = (const float*)d_in[8];
    const float* Wa2 = (const float*)d_in[9];
    const float* ba2 = (const float*)d_in[10];
    float* out = (float*)d_out;

    const int* src = ei;
    const int* dst = ei + E_EDGES;

    // workspace (~25 MB)
    unsigned short* xb   = (unsigned short*)d_ws;          // [N,64] bf16
    unsigned short* h1b  = xb + (size_t)N_NODES * 64;      // [N,64] bf16
    unsigned short* h2b  = h1b + (size_t)N_NODES * 64;     // [N,64] bf16
    unsigned short* WT1  = h2b + (size_t)N_NODES * 64;     // [64,512] bf16
    unsigned short* WT2  = WT1 + 64 * 512;
    unsigned short* Wa1T = WT2 + 64 * 512;                 // [128,64] bf16
    unsigned short* Wa2T = Wa1T + 8192;                    // [64,128] bf16
    int* cnt      = (int*)(Wa2T + 8192);                   // KEYS
    int* bsum     = cnt + KEYS;                            // 512
    int* chunkoff = bsum + 512;                            // 512
    int* done     = chunkoff + 512;                        // 64 (1 used)
    int* elist    = done + 64;                             // E packed (src | t<<16)

    const int eBlk = (E_EDGES + 255) / 256;               // 3125
    const int cBlk = N_NODES / DPB;                       // 3125 (exact)
    const int aBlk = (N_NODES + 63) / 64;                 // 782

    hipMemsetAsync(cnt, 0, (KEYS + 512 + 512 + 64) * sizeof(int), stream);
    prep_hist<<<PBLK_X + PBLK_W + PBLK_A + PBLK_H, 256, 0, stream>>>(
        x, Wt1, Wt2, Wa1, Wa2, dst, tix, xb, WT1, WT2, Wa1T, Wa2T, cnt);
    scan_all<<<NBLK1, 256, 0, stream>>>(cnt, bsum, chunkoff, done);
    scatter_edges<<<eBlk, 256, 0, stream>>>(src, dst, tix, cnt, chunkoff, elist);

    fused_conv<<<cBlk, 512, 0, stream>>>(xb,  WT1, bt1, cnt, chunkoff, elist, h1b);
    fused_conv<<<cBlk, 512, 0, stream>>>(h1b, WT2, bt2, cnt, chunkoff, elist, h2b);

    adv_mfma<<<aBlk, 256, 0, stream>>>(h2b, Wa1T, ba1, Wa2T, ba2, h1b, out);
}

// Round 15
// 289.935 us; speedup vs baseline: 1.1774x; 1.0819x over previous
//
#include <hip/hip_runtime.h>

#define N_NODES 50000
#define C_FEAT  64
#define E_EDGES 800000
#define KEYS    400000          // dst*8 + t
#define NBLK1   391             // ceil(KEYS/1024)
#define DPB     16              // dsts per conv block -> 16 MFMA rows
#define PBLK_X  1563            // x->bf16 cvt blocks (8 elems/thread, last partial)
#define PBLK_W  128             // Wt transpose blocks
#define PBLK_A  64              // Wa1T/Wa2T transpose blocks (2 x 8192)
#define PBLK_H  3128            // hist blocks: 8 XCD groups x 391 tiles
#define DPART   6250            // dsts per XCD partition

typedef __attribute__((ext_vector_type(8))) short short8;
typedef __attribute__((ext_vector_type(4))) float f32x4;

__device__ __forceinline__ float bf2f(unsigned short u) {
    union { unsigned int i; float f; } v; v.i = ((unsigned int)u) << 16; return v.f;
}
__device__ __forceinline__ unsigned short f2bf(float f) {
    union { float f; unsigned int i; } v; v.f = f;
    unsigned int r = v.i + 0x7fff + ((v.i >> 16) & 1);   // RNE
    return (unsigned short)(r >> 16);
}

// -------- prep (x->bf16, Wt->WT bf16, Wa->WaT bf16) + XCD-partitioned hist --------
__global__ __launch_bounds__(256) void prep_hist(const float* __restrict__ x,
                                                 const float* __restrict__ W1,
                                                 const float* __restrict__ W2,
                                                 const float* __restrict__ Wa1,
                                                 const float* __restrict__ Wa2,
                                                 const int* __restrict__ dst,
                                                 const int* __restrict__ tix,
                                                 unsigned short* __restrict__ xb,
                                                 unsigned short* __restrict__ WT1,
                                                 unsigned short* __restrict__ WT2,
                                                 unsigned short* __restrict__ Wa1T,
                                                 unsigned short* __restrict__ Wa2T,
                                                 int* __restrict__ cnt) {
    const int b = blockIdx.x;
    if (b < PBLK_X) {
        int base = (b * 256 + threadIdx.x) * 8;
        if (base < N_NODES * 64) {
            float4 a = *(const float4*)(x + base);
            float4 c = *(const float4*)(x + base + 4);
            short8 o;
            o[0] = (short)f2bf(a.x); o[1] = (short)f2bf(a.y);
            o[2] = (short)f2bf(a.z); o[3] = (short)f2bf(a.w);
            o[4] = (short)f2bf(c.x); o[5] = (short)f2bf(c.y);
            o[6] = (short)f2bf(c.z); o[7] = (short)f2bf(c.w);
            *(short8*)(xb + base) = o;
        }
    } else if (b < PBLK_X + PBLK_W) {
        int i = (b - PBLK_X) * 256 + threadIdx.x;      // 32768
        int n = i >> 9, k = i & 511;
        WT1[i] = f2bf(W1[k * 64 + n]);
        WT2[i] = f2bf(W2[k * 64 + n]);
    } else if (b < PBLK_X + PBLK_W + PBLK_A) {
        int i = (b - PBLK_X - PBLK_W) * 256 + threadIdx.x;   // 0..16383
        if (i < 8192) {                                // Wa1T[128][64] <- Wa1[64][128]
            int n = i >> 6, k = i & 63;
            Wa1T[i] = f2bf(Wa1[k * 128 + n]);
        } else {                                       // Wa2T[64][128] <- Wa2[128][64]
            int ii = i - 8192;
            int n = ii >> 7, k = ii & 127;
            Wa2T[ii] = f2bf(Wa2[k * 64 + n]);
        }
    } else {
        // XCD-partitioned hist: group g (blockIdx%8 ~ XCD) handles dst in [g*6250,(g+1)*6250)
        int bb = b - PBLK_X - PBLK_W - PBLK_A;         // 0..3127
        const int g = bb & 7;
        const int tile = bb >> 3;                      // 0..390
        int e = tile * 2048 + threadIdx.x;
        #pragma unroll
        for (int it = 0; it < 8; ++it, e += 256) {
            if (e < E_EDGES) {
                int d = dst[e];
                if (d / DPART == g)
                    atomicAdd(&cnt[d * 8 + tix[e]], 1);
            }
        }
    }
}

// -------- scan_all: per-chunk local scan; LAST block scans chunk totals --------
__global__ __launch_bounds__(256) void scan_all(int* __restrict__ cnt,
                                                int* __restrict__ bsum,
                                                int* __restrict__ chunkoff,
                                                int* __restrict__ done) {
    __shared__ int wsum[4];
    __shared__ int ticket;
    const int tid = threadIdx.x;
    const int lane = tid & 63;
    const int wave = tid >> 6;
    const int i4 = blockIdx.x * 256 + tid;
    int4 v = make_int4(0, 0, 0, 0);
    const bool ok = (i4 * 4 < KEYS);
    if (ok) v = ((const int4*)cnt)[i4];
    int s = v.x + v.y + v.z + v.w;
    int sc = s;
    #pragma unroll
    for (int d = 1; d < 64; d <<= 1) {
        int o = __shfl_up(sc, d, 64);
        if (lane >= d) sc += o;
    }
    if (lane == 63) wsum[wave] = sc;
    __syncthreads();
    int wbase = 0;
    #pragma unroll
    for (int w = 0; w < 4; ++w) wbase += (w < wave) ? wsum[w] : 0;
    int base = wbase + sc - s;
    int4 o;
    o.x = base;
    o.y = base + v.x;
    o.z = o.y + v.y;
    o.w = o.z + v.z;
    if (ok) ((int4*)cnt)[i4] = o;
    if (tid == 255) {
        bsum[blockIdx.x] = wbase + sc;
        __threadfence();
        ticket = atomicAdd(done, 1);
    }
    __syncthreads();
    if (ticket == NBLK1 - 1 && wave == 0) {
        int carry = 0;
        #pragma unroll
        for (int g = 0; g < (NBLK1 + 63) / 64; ++g) {
            int j = g * 64 + lane;
            int val = (j < NBLK1) ? atomicAdd(&bsum[j], 0) : 0;
            int scn = val;
            #pragma unroll
            for (int d = 1; d < 64; d <<= 1) {
                int oo = __shfl_up(scn, d, 64);
                if (lane >= d) scn += oo;
            }
            if (j < NBLK1) chunkoff[j] = carry + scn - val;
            carry += __shfl(scn, 63, 64);
        }
    }
}

// -------- XCD-partitioned scatter: group g writes only dst in its range --------
// All writers of an elist line live on one XCD -> lines accumulate in that L2.
__global__ __launch_bounds__(256) void scatter_edges(const int* __restrict__ src,
                                                     const int* __restrict__ dst,
                                                     const int* __restrict__ tix,
                                                     int* __restrict__ cursor,
                                                     const int* __restrict__ chunkoff,
                                                     int* __restrict__ elist) {
    const int g = blockIdx.x & 7;                    // partition (XCD-affine)
    const int tile = blockIdx.x >> 3;                // 0..390
    int e = tile * 2048 + threadIdx.x;
    #pragma unroll
    for (int it = 0; it < 8; ++it, e += 256) {
        if (e < E_EDGES) {
            int d = dst[e];
            if (d / DPART == g) {
                int t = tix[e];
                int key = d * 8 + t;
                int pos = chunkoff[key >> 10] + atomicAdd(&cursor[key], 1);
                elist[pos] = src[e] | (t << 16);     // plain store: let L2 cache it
            }
        }
    }
}

// -------- fused conv: 512 threads, 8 waves x 2 dsts, unroll 8/4/2/1, MFMA --------
#define FLUSH(T, V)                                                                   \
    { int _t = (T);                                                                   \
      if (_t != cur) { scat[dl][cur * 64 + c] = f2bf(acc); acc = 0.f; cur = _t; }     \
      acc += (V); }

#define EDGE(K)                                                                       \
    int p##K = __builtin_amdgcn_readlane(pv, e + K);                                  \
    float v##K = bf2f(Xb[(size_t)(p##K & 0xffff) * 64 + c]);

__global__ __launch_bounds__(512, 8) void fused_conv(const unsigned short* __restrict__ Xb,
                                                     const unsigned short* __restrict__ WT,
                                                     const float* __restrict__ bias,
                                                     const int* __restrict__ segend,   // local ends
                                                     const int* __restrict__ chunkoff,
                                                     const int* __restrict__ elist,
                                                     unsigned short* __restrict__ Hb) {
    __shared__ unsigned short scat[DPB][520];
    const int lane = threadIdx.x & 63;
    const int wave = threadIdx.x >> 6;               // 0..7
    const int dbase = blockIdx.x * DPB;
    const int c = lane;

    {   // zero own 2 rows
        short8 z = {};
        *(short8*)&scat[wave * 2 + 0][lane * 8] = z;
        *(short8*)&scat[wave * 2 + 1][lane * 8] = z;
    }

    int sbeg[2], send_[2], pvw[2];
    #pragma unroll
    for (int q = 0; q < 2; ++q) {
        const int d = dbase + wave * 2 + q;
        const int k0 = d * 8;
        sbeg[q]  = (d == 0) ? 0 : chunkoff[(k0 - 1) >> 10] + segend[k0 - 1];
        send_[q] = chunkoff[(k0 + 7) >> 10] + segend[k0 + 7];
    }
    #pragma unroll
    for (int q = 0; q < 2; ++q)
        pvw[q] = (lane < send_[q] - sbeg[q]) ? elist[sbeg[q] + lane] : 0;

    #pragma unroll
    for (int q = 0; q < 2; ++q) {
        const int dl = wave * 2 + q;
        int i = sbeg[q];
        const int end = send_[q];
        int pv = pvw[q];
        int cur = 0;
        float acc = 0.f;
        while (i < end) {
            int cnt = end - i; cnt = (cnt > 64) ? 64 : cnt;
            int e = 0;
            for (; e + 7 < cnt; e += 8) {
                EDGE(0) EDGE(1) EDGE(2) EDGE(3) EDGE(4) EDGE(5) EDGE(6) EDGE(7)
                FLUSH(p0 >> 16, v0) FLUSH(p1 >> 16, v1)
                FLUSH(p2 >> 16, v2) FLUSH(p3 >> 16, v3)
                FLUSH(p4 >> 16, v4) FLUSH(p5 >> 16, v5)
                FLUSH(p6 >> 16, v6) FLUSH(p7 >> 16, v7)
            }
            if (e + 3 < cnt) {                        // tail tier 4
                EDGE(0) EDGE(1) EDGE(2) EDGE(3)
                FLUSH(p0 >> 16, v0) FLUSH(p1 >> 16, v1)
                FLUSH(p2 >> 16, v2) FLUSH(p3 >> 16, v3)
                e += 4;
            }
            if (e + 1 < cnt) {                        // tail tier 2
                EDGE(0) EDGE(1)
                FLUSH(p0 >> 16, v0) FLUSH(p1 >> 16, v1)
                e += 2;
            }
            if (e < cnt) {                            // tail tier 1
                EDGE(0)
                FLUSH(p0 >> 16, v0)
            }
            i += 64;
            if (i < end) pv = (lane < end - i) ? elist[i + lane] : 0;
        }
        scat[dl][cur * 64 + c] = f2bf(acc);
    }
    __syncthreads();

    // MFMA [16,512]@[512,64] on waves 0..3; C/D col=lane&15, row=quad*4+r (m89/m91)
    if (wave < 4) {
        const int m = lane & 15;
        const int quad = lane >> 4;
        const int n0 = wave * 16;
        f32x4 acc4 = {0.f, 0.f, 0.f, 0.f};
        const unsigned short* wrow = WT + (size_t)(n0 + m) * 512;
        #pragma unroll
        for (int kc = 0; kc < 16; ++kc) {
            short8 af = *(const short8*)&scat[m][kc * 32 + quad * 8];
            short8 bf = *(const short8*)(wrow + kc * 32 + quad * 8);
            acc4 = __builtin_amdgcn_mfma_f32_16x16x32_bf16(af, bf, acc4, 0, 0, 0);
        }
        const int col = n0 + m;
        const float bcol = bias[col];
        #pragma unroll
        for (int r = 0; r < 4; ++r) {
            int node = dbase + quad * 4 + r;
            Hb[(size_t)node * 64 + col] = f2bf(fmaxf(acc4[r] + bcol, 0.f));
        }
    }
}

// -------- adversary MLP via MFMA + h1 residual (R13-proven) --------
__global__ __launch_bounds__(256) void adv_mfma(const unsigned short* __restrict__ h2b,
                                                const unsigned short* __restrict__ Wa1T, // [128][64] bf16
                                                const float* __restrict__ ba1,           // [128]
                                                const unsigned short* __restrict__ Wa2T, // [64][128] bf16
                                                const float* __restrict__ ba2,           // [64]
                                                const unsigned short* __restrict__ h1b,
                                                float* __restrict__ out) {
    __shared__ unsigned short sH[64][72];
    __shared__ unsigned short sT[64][136];
    const int nbase = blockIdx.x * 64;
    const int tid = threadIdx.x;
    const int lane = tid & 63;
    const int wave = tid >> 6;
    const int m = lane & 15;
    const int quad = lane >> 4;
    const int r0 = wave * 16;

    #pragma unroll
    for (int i = 0; i < 2; ++i) {
        int idx = tid * 2 + i;
        int row = idx >> 3;
        int c8  = (idx & 7) * 8;
        int node = nbase + row;
        short8 u = {};
        if (node < N_NODES)
            u = *(const short8*)(h2b + (size_t)node * C_FEAT + c8);
        *(short8*)&sH[row][c8] = u;
    }
    __syncthreads();

    {   // GEMM1: [16,64] @ [64,128] per wave -> sT rows r0..r0+15
        f32x4 acc1[8];
        #pragma unroll
        for (int ct = 0; ct < 8; ++ct) acc1[ct] = (f32x4){0.f, 0.f, 0.f, 0.f};
        #pragma unroll
        for (int kc = 0; kc < 2; ++kc) {
            short8 af = *(const short8*)&sH[r0 + m][kc * 32 + quad * 8];
            #pragma unroll
            for (int ct = 0; ct < 8; ++ct) {
                short8 bf = *(const short8*)(Wa1T + (size_t)(ct * 16 + m) * 64 + kc * 32 + quad * 8);
                acc1[ct] = __builtin_amdgcn_mfma_f32_16x16x32_bf16(af, bf, acc1[ct], 0, 0, 0);
            }
        }
        #pragma unroll
        for (int ct = 0; ct < 8; ++ct) {
            const int col = ct * 16 + m;
            const float b1 = ba1[col];
            #pragma unroll
            for (int r = 0; r < 4; ++r)
                sT[r0 + quad * 4 + r][col] = f2bf(fmaxf(acc1[ct][r] + b1, 0.f));
        }
    }
    __syncthreads();

    {   // GEMM2: [16,128] @ [128,64] per wave -> out rows r0..r0+15 (+ba2 +h1)
        f32x4 acc2[4];
        #pragma unroll
        for (int ct = 0; ct < 4; ++ct) acc2[ct] = (f32x4){0.f, 0.f, 0.f, 0.f};
        #pragma unroll
        for (int kc = 0; kc < 4; ++kc) {
            short8 af = *(const short8*)&sT[r0 + m][kc * 32 + quad * 8];
            #pragma unroll
            for (int ct = 0; ct < 4; ++ct) {
                short8 bf = *(const short8*)(Wa2T + (size_t)(ct * 16 + m) * 128 + kc * 32 + quad * 8);
                acc2[ct] = __builtin_amdgcn_mfma_f32_16x16x32_bf16(af, bf, acc2[ct], 0, 0, 0);
            }
        }
        #pragma unroll
        for (int ct = 0; ct < 4; ++ct) {
            const int col = ct * 16 + m;
            const float b2 = ba2[col];
            #pragma unroll
            for (int r = 0; r < 4; ++r) {
                int node = nbase + r0 + quad * 4 + r;
                if (node < N_NODES) {
                    float val = acc2[ct][r] + b2 + bf2f(h1b[(size_t)node * 64 + col]);
                    out[(size_t)node * 64 + col] = val;
                }
            }
        }
    }
}

extern "C" void kernel_launch(void* const* d_in, const int* in_sizes, int n_in,
                              void* d_out, int out_size, void* d_ws, size_t ws_size,
                              hipStream_t stream) {
    const float* x   = (const float*)d_in[0];
    const int*   ei  = (const int*)d_in[1];
    const int*   tix = (const int*)d_in[2];
    const float* Wt1 = (const float*)d_in[3];
    const float* bt1 = (const float*)d_in[4];
    const float* Wt2 = (const float*)d_in[5];
    const float* bt2 = (const float*)d_in[6];
    const float* Wa1 = (const float*)d_in[7];
    const float* ba1 = (const float*)d_in[8];
    const float* Wa2 = (const float*)d_in[9];
    const float* ba2 = (const float*)d_in[10];
    float* out = (float*)d_out;

    const int* src = ei;
    const int* dst = ei + E_EDGES;

    // workspace (~25 MB)
    unsigned short* xb   = (unsigned short*)d_ws;          // [N,64] bf16
    unsigned short* h1b  = xb + (size_t)N_NODES * 64;      // [N,64] bf16
    unsigned short* h2b  = h1b + (size_t)N_NODES * 64;     // [N,64] bf16
    unsigned short* WT1  = h2b + (size_t)N_NODES * 64;     // [64,512] bf16
    unsigned short* WT2  = WT1 + 64 * 512;
    unsigned short* Wa1T = WT2 + 64 * 512;                 // [128,64] bf16
    unsigned short* Wa2T = Wa1T + 8192;                    // [64,128] bf16
    int* cnt      = (int*)(Wa2T + 8192);                   // KEYS
    int* bsum     = cnt + KEYS;                            // 512
    int* chunkoff = bsum + 512;                            // 512
    int* done     = chunkoff + 512;                        // 64 (1 used)
    int* elist    = done + 64;                             // E packed (src | t<<16)

    const int cBlk = N_NODES / DPB;                       // 3125 (exact)
    const int aBlk = (N_NODES + 63) / 64;                 // 782

    hipMemsetAsync(cnt, 0, (KEYS + 512 + 512 + 64) * sizeof(int), stream);
    prep_hist<<<PBLK_X + PBLK_W + PBLK_A + PBLK_H, 256, 0, stream>>>(
        x, Wt1, Wt2, Wa1, Wa2, dst, tix, xb, WT1, WT2, Wa1T, Wa2T, cnt);
    scan_all<<<NBLK1, 256, 0, stream>>>(cnt, bsum, chunkoff, done);
    scatter_edges<<<8 * 391, 256, 0, stream>>>(src, dst, tix, cnt, chunkoff, elist);

    fused_conv<<<cBlk, 512, 0, stream>>>(xb,  WT1, bt1, cnt, chunkoff, elist, h1b);
    fused_conv<<<cBlk, 512, 0, stream>>>(h1b, WT2, bt2, cnt, chunkoff, elist, h2b);

    adv_mfma<<<aBlk, 256, 0, stream>>>(h2b, Wa1T, ba1, Wa2T, ba2, h1b, out);
}